// Round 1
// baseline (1145.083 us; speedup 1.0000x reference)
//
#include <hip/hip_runtime.h>

#define NTOT 4096
#define NBATCH 4
#define KNN 20
#define JSPLIT 8
#define JSPLIT3 4
#define KSUB 16
#define KMRG 28
#define CSLOT 256  // per-point candidate slot (256 entries, filled by both paths)

constexpr float NEG_INF = -3.0e38f;

typedef __attribute__((ext_vector_type(8))) short bf16x8;
typedef __attribute__((ext_vector_type(4))) float f32x4;

__device__ __forceinline__ unsigned pk(float f, int j) {
  unsigned u = __float_as_uint(f);
  u = (u & 0x80000000u) ? ~u : (u | 0x80000000u);
  return (u & 0xFFFFF000u) | (unsigned)j;
}

__device__ __forceinline__ void pins16(unsigned u, unsigned (&tv)[KSUB]) {
  if (u > tv[0]) {
    tv[0] = u;
#pragma unroll
    for (int x = 1; x < KSUB; x++) {
      unsigned mn = min(tv[0], tv[x]);
      unsigned mx = max(tv[0], tv[x]);
      tv[0] = mn;
      tv[x] = mx;
    }
  }
}

// ---------------- prep: fold BN scale into weights ----------------
__global__ void prep_w(const float* __restrict__ W, const float* __restrict__ gg,
                       const float* __restrict__ bb, const float* __restrict__ mm,
                       const float* __restrict__ vv, float* __restrict__ Wc,
                       float* __restrict__ bias, int O, int C) {
  int t = blockIdx.x * 256 + threadIdx.x;
  if (t >= 2 * O * C) return;
  int o2 = t / C, c = t - o2 * C;
  int o = (o2 < O) ? o2 : o2 - O;
  float s = gg[o] * rsqrtf(vv[o] + 1e-5f);
  float w = (o2 < O) ? W[o * 2 * C + c] * s
                     : (W[o * 2 * C + C + c] - W[o * 2 * C + c]) * s;
  Wc[o2 * C + c] = w;
  if (o2 >= O && c == 0) bias[o] = bb[o] - mm[o] * s;
}

// ---------------- split-bf16 conversion: x = hi + lo ----------------
__global__ void cvt_k(const float* __restrict__ f, ushort* __restrict__ hi,
                      ushort* __restrict__ lo) {
  int p = blockIdx.x * 256 + threadIdx.x;
  float x = f[p];
  unsigned u = __float_as_uint(x);
  unsigned h = (u + 0x7FFFu + ((u >> 16) & 1u)) >> 16;
  float hf = __uint_as_float(h << 16);
  float r = x - hf;
  unsigned v = __float_as_uint(r);
  unsigned l = (v + 0x7FFFu + ((v >> 16) & 1u)) >> 16;
  hi[p] = (ushort)h;
  lo[p] = (ushort)l;
}

// ---------------- half squared norms (exact fp32) ----------------
template <int C>
__global__ void sqh_k(const float* __restrict__ f, float* __restrict__ sqh) {
  int p = blockIdx.x * 256 + threadIdx.x;
  const float* r = f + (size_t)p * C;
  float s = 0.f;
#pragma unroll
  for (int c4 = 0; c4 < C / 4; c4++) {
    float4 v = *(const float4*)&r[c4 * 4];
    s += v.x * v.x + v.y * v.y + v.z * v.z + v.w * v.w;
  }
  sqh[p] = 0.5f * s;
}

// ---------------- KNN C=3 stage 1: 4-way j-split, 16 sub-lists/row ----------
// Grid NBATCH*64*4 = 1024 blocks (4 blocks/CU). Each block: 64 rows x j-range
// of 1024. Sub-list id = js*4+q -> 16 lists x 16 = 256 = CSLOT exactly.
__global__ __launch_bounds__(256) void knn3_g(const float* __restrict__ feat,
                                              unsigned* __restrict__ cval) {
  __shared__ __align__(16) float sA[64 * 4];

  int tid = threadIdx.x;
  int js = blockIdx.x & (JSPLIT3 - 1);
  int rb = (blockIdx.x >> 2) & 63;
  int b = blockIdx.x >> 8;
  int row0 = rb * 64;
  int r = tid >> 2, q = tid & 3;
  int i = row0 + r;
  const float* fb = feat + (size_t)b * NTOT * 3;

  float c0 = fb[(size_t)i * 3 + 0];
  float c1 = fb[(size_t)i * 3 + 1];
  float c2 = fb[(size_t)i * 3 + 2];

  unsigned tv[KSUB];
#pragma unroll
  for (int t = 0; t < KSUB; t++) tv[t] = 0u;

  for (int jt = js * (NTOT / JSPLIT3); jt < (js + 1) * (NTOT / JSPLIT3); jt += 64) {
    __syncthreads();
    if (tid < 64) {
      sA[tid * 4 + 0] = fb[(size_t)(jt + tid) * 3 + 0];
      sA[tid * 4 + 1] = fb[(size_t)(jt + tid) * 3 + 1];
      sA[tid * 4 + 2] = fb[(size_t)(jt + tid) * 3 + 2];
    }
    __syncthreads();

#pragma unroll
    for (int cc = 0; cc < 4; cc++) {
      float vq[4];
#pragma unroll
      for (int u = 0; u < 4; u++) {
        int jl = (cc * 4 + u) * 4 + q;
        float d0 = c0 - sA[jl * 4];
        float d1 = c1 - sA[jl * 4 + 1];
        float d2 = c2 - sA[jl * 4 + 2];
        vq[u] = -(d0 * d0 + d1 * d1 + d2 * d2);
      }
      float m4 = fmaxf(fmaxf(vq[0], vq[1]), fmaxf(vq[2], vq[3]));
      if (pk(m4, 0xFFF) > tv[0]) {
#pragma unroll
        for (int u = 0; u < 4; u++)
          pins16(pk(vq[u], jt + (cc * 4 + u) * 4 + q), tv);
      }
    }
  }

  int p = b * NTOT + row0 + r;
  int sub = js * 4 + q;  // 0..15
  unsigned* dst = cval + (size_t)p * CSLOT + sub * 16;
#pragma unroll
  for (int t4 = 0; t4 < 4; t4++) {
    uint4 o;
    o.x = tv[t4 * 4 + 0];
    o.y = tv[t4 * 4 + 1];
    o.z = tv[t4 * 4 + 2];
    o.w = tv[t4 * 4 + 3];
    *(uint4*)&dst[t4 * 4] = o;
  }
}

// ---------------- KNN stage 1 (C=64/128): split-bf16 MFMA dot ----------
// LDS: staging (Ah/Al/Bh/Bl, 40960B) OVERLAID with Dt (34816B) -> 40960B
// total => 4 blocks/CU (vs 2 before). sqB moved to registers.
template <int C>
__global__ __launch_bounds__(256, 4) void knn_m(const ushort* __restrict__ Xhi,
                                                const ushort* __restrict__ Xlo,
                                                const float* __restrict__ sqh,
                                                unsigned* __restrict__ cval) {
  constexpr int RS = 40;  // LDS row stride (bf16): 32 data + 8 pad
  __shared__ __align__(16) char smem[4 * 128 * RS * sizeof(ushort)];  // 40960
  ushort* Ah = (ushort*)smem;
  ushort* Al = Ah + 128 * RS;
  ushort* Bh = Al + 128 * RS;
  ushort* Bl = Bh + 128 * RS;
  float* Dt = (float*)smem;  // 128*68 floats = 34816B, live only post-MFMA

  int tid = threadIdx.x;
  int js = blockIdx.x & (JSPLIT - 1);
  int it = (blockIdx.x >> 3) & 31;
  int b = blockIdx.x >> 8;
  int i0 = it * 128;
  const ushort* xh = Xhi + (size_t)b * NTOT * C;
  const ushort* xl = Xlo + (size_t)b * NTOT * C;

  int l = tid & 63, wid = tid >> 6;
  int wi = wid & 1, wj = wid >> 1;
  int n = l & 15, quad = l >> 4;
  // Dt-read ownership: lanes 0..7 hit 8 distinct bank windows (stride 68
  // => window = row&7), so consecutive-lane phase groups are conflict-free.
  int selr = (wid << 5) | (l & 31);  // row 0..127 (bijective over block)
  int sels = l >> 5;                 // which 32-col half

  unsigned tv[KSUB];
#pragma unroll
  for (int t = 0; t < KSUB; t++) tv[t] = 0u;

  for (int jt = 0; jt < NTOT / (128 * JSPLIT); jt++) {
    int j0 = js * (NTOT / JSPLIT) + jt * 128;

    // per-thread -|xj|^2/2 values for this wave's j-columns (replaces sqB LDS)
    float sqv[4];
#pragma unroll
    for (int tj = 0; tj < 4; tj++)
      sqv[tj] = sqh[b * NTOT + j0 + wj * 64 + tj * 16 + n];

    f32x4 acc[4][4];
#pragma unroll
    for (int ti = 0; ti < 4; ti++)
#pragma unroll
      for (int tj = 0; tj < 4; tj++) acc[ti][tj] = (f32x4)(0.f);

    for (int kc = 0; kc < C; kc += 32) {
      __syncthreads();
#pragma unroll
      for (int l2 = 0; l2 < 2; l2++) {
        int e = tid + 256 * l2;
        int rr = e >> 2, ko = (e & 3) * 8;
        *(uint4*)&Ah[rr * RS + ko] = *(const uint4*)&xh[(size_t)(i0 + rr) * C + kc + ko];
        *(uint4*)&Al[rr * RS + ko] = *(const uint4*)&xl[(size_t)(i0 + rr) * C + kc + ko];
        *(uint4*)&Bh[rr * RS + ko] = *(const uint4*)&xh[(size_t)(j0 + rr) * C + kc + ko];
        *(uint4*)&Bl[rr * RS + ko] = *(const uint4*)&xl[(size_t)(j0 + rr) * C + kc + ko];
      }
      __syncthreads();

      bf16x8 ah[4], al[4];
#pragma unroll
      for (int ti = 0; ti < 4; ti++) {
        int row = wi * 64 + ti * 16 + n;
        ah[ti] = *(const bf16x8*)&Ah[row * RS + quad * 8];
        al[ti] = *(const bf16x8*)&Al[row * RS + quad * 8];
      }
#pragma unroll
      for (int tj = 0; tj < 4; tj++) {
        int row = wj * 64 + tj * 16 + n;
        bf16x8 bh = *(const bf16x8*)&Bh[row * RS + quad * 8];
        bf16x8 bl = *(const bf16x8*)&Bl[row * RS + quad * 8];
#pragma unroll
        for (int ti = 0; ti < 4; ti++) {
          acc[ti][tj] = __builtin_amdgcn_mfma_f32_16x16x32_bf16(ah[ti], bh, acc[ti][tj], 0, 0, 0);
          acc[ti][tj] = __builtin_amdgcn_mfma_f32_16x16x32_bf16(ah[ti], bl, acc[ti][tj], 0, 0, 0);
          acc[ti][tj] = __builtin_amdgcn_mfma_f32_16x16x32_bf16(al[ti], bh, acc[ti][tj], 0, 0, 0);
        }
      }
    }
    // all fragment reads done before Dt overwrites the staging buffers
    __syncthreads();

    // phase A: waves wj==0 hold j-cols 0..63
    if (wj == 0) {
#pragma unroll
      for (int ti = 0; ti < 4; ti++)
#pragma unroll
        for (int tj = 0; tj < 4; tj++) {
          float q = sqv[tj];
#pragma unroll
          for (int r = 0; r < 4; r++)
            Dt[(wi * 64 + ti * 16 + quad * 4 + r) * 68 + tj * 16 + n] =
                acc[ti][tj][r] - q;
        }
    }
    __syncthreads();
#pragma unroll
    for (int t4 = 0; t4 < 8; t4++) {
      float4 v = *(const float4*)&Dt[selr * 68 + sels * 32 + t4 * 4];
      float m4 = fmaxf(fmaxf(v.x, v.y), fmaxf(v.z, v.w));
      if (pk(m4, 0xFFF) > tv[0]) {
        int jb = j0 + sels * 32 + t4 * 4;
        pins16(pk(v.x, jb + 0), tv);
        pins16(pk(v.y, jb + 1), tv);
        pins16(pk(v.z, jb + 2), tv);
        pins16(pk(v.w, jb + 3), tv);
      }
    }
    __syncthreads();
    // phase B: waves wj==1 hold j-cols 64..127
    if (wj == 1) {
#pragma unroll
      for (int ti = 0; ti < 4; ti++)
#pragma unroll
        for (int tj = 0; tj < 4; tj++) {
          float q = sqv[tj];
#pragma unroll
          for (int r = 0; r < 4; r++)
            Dt[(wi * 64 + ti * 16 + quad * 4 + r) * 68 + tj * 16 + n] =
                acc[ti][tj][r] - q;
        }
    }
    __syncthreads();
#pragma unroll
    for (int t4 = 0; t4 < 8; t4++) {
      float4 v = *(const float4*)&Dt[selr * 68 + sels * 32 + t4 * 4];
      float m4 = fmaxf(fmaxf(v.x, v.y), fmaxf(v.z, v.w));
      if (pk(m4, 0xFFF) > tv[0]) {
        int jb = j0 + 64 + sels * 32 + t4 * 4;
        pins16(pk(v.x, jb + 0), tv);
        pins16(pk(v.y, jb + 1), tv);
        pins16(pk(v.z, jb + 2), tv);
        pins16(pk(v.w, jb + 3), tv);
      }
    }
    // next iteration's kc-loop barrier protects Dt reads vs restaging
  }

  int p = b * NTOT + i0 + selr;
  int sub = js * 2 + sels;  // 0..15
  unsigned* dst = cval + (size_t)p * CSLOT + sub * 16;
#pragma unroll
  for (int t4 = 0; t4 < 4; t4++) {
    uint4 o;
    o.x = tv[t4 * 4 + 0];
    o.y = tv[t4 * 4 + 1];
    o.z = tv[t4 * 4 + 2];
    o.w = tv[t4 * 4 + 3];
    *(uint4*)&dst[t4 * 4] = o;
  }
}

// ---------------- wave-per-point merge + exact refine ----------------
template <int C, int NC>
__global__ __launch_bounds__(256) void kref_w(const float* __restrict__ feat,
                                              const unsigned* __restrict__ cval,
                                              int* __restrict__ outidx) {
  int tid = threadIdx.x;
  int lane = tid & 63;
  int p = blockIdx.x * 4 + (tid >> 6);
  int b = p >> 12;
  int i = p & (NTOT - 1);
  const float* fb = feat + (size_t)b * NTOT * C;

  unsigned c0 = 0, c1 = 0, c2 = 0, c3 = 0;
  if (NC == 256) {
    uint4 cc = *(const uint4*)&cval[(size_t)p * CSLOT + lane * 4];
    c0 = cc.x;
    c1 = cc.y;
    c2 = cc.z;
    c3 = cc.w;
  } else {
    c0 = cval[(size_t)p * CSLOT + lane];
  }

  int jl[KMRG];
  int myj = -1;
#pragma unroll
  for (int t = 0; t < KMRG; t++) {
    unsigned m = max(max(c0, c1), max(c2, c3));
#pragma unroll
    for (int s = 1; s < 64; s <<= 1) m = max(m, (unsigned)__shfl_xor((int)m, s));
    jl[t] = (int)(m & 0xFFFu);
    if (lane == t) myj = (int)(m & 0xFFFu);
    if (c0 == m) c0 = 0;
    if (c1 == m) c1 = 0;
    if (c2 == m) c2 = 0;
    if (c3 == m) c3 = 0;
  }

  float myval = NEG_INF;
  if (C == 3) {
    if (lane < KMRG) {
      float x0 = fb[(size_t)i * 3 + 0];
      float x1 = fb[(size_t)i * 3 + 1];
      float x2 = fb[(size_t)i * 3 + 2];
      float y0 = fb[(size_t)myj * 3 + 0];
      float y1 = fb[(size_t)myj * 3 + 1];
      float y2 = fb[(size_t)myj * 3 + 2];
      float d0 = x0 - y0, d1 = x1 - y1, d2 = x2 - y2;
      myval = -(d0 * d0 + d1 * d1 + d2 * d2);
    }
  } else {
    constexpr int CPL = (C >= 64) ? C / 64 : 1;  // floats per lane
    float fx0, fx1 = 0.f;
    if (CPL == 2) {
      float2 xv = *(const float2*)&fb[(size_t)i * C + lane * 2];
      fx0 = xv.x;
      fx1 = xv.y;
    } else {
      fx0 = fb[(size_t)i * C + lane];
    }
#pragma unroll
    for (int u = 0; u < KMRG; u++) {
      int j = jl[u];
      float d;
      if (CPL == 2) {
        float2 yv = *(const float2*)&fb[(size_t)j * C + lane * 2];
        float dx = fx0 - yv.x, dy = fx1 - yv.y;
        d = dx * dx + dy * dy;
      } else {
        float y = fb[(size_t)j * C + lane];
        float dx = fx0 - y;
        d = dx * dx;
      }
#pragma unroll
      for (int s = 1; s < 64; s <<= 1) d += __shfl_xor(d, s);
      if (lane == u) myval = -d;
    }
  }

  // final exact top-20 across lanes (lane u holds candidate u)
  int wj = 0;
#pragma unroll
  for (int t = 0; t < KNN; t++) {
    float bv = myval;
    int bx = myj;
#pragma unroll
    for (int s = 1; s < 64; s <<= 1) {
      float ov = __shfl_xor(bv, s);
      int ox = __shfl_xor(bx, s);
      if (ov > bv || (ov == bv && ox < bx)) {
        bv = ov;
        bx = ox;
      }
    }
    if (lane == t) wj = bx;
    if (myj == bx) myval = NEG_INF;
  }
  if (lane < KNN) outidx[(size_t)p * KNN + lane] = wj;
}

// ---------------- 128x128 GEMM (K>=16): Y = A * Wc^T (+bias on V half) ------
__global__ __launch_bounds__(256) void gemm128(const float* __restrict__ A,
                                               const float* __restrict__ Wc,
                                               const float* __restrict__ bias,
                                               float* __restrict__ Y, int K, int N2,
                                               int O) {
  constexpr int P = 140;
  __shared__ float As[16 * P];
  __shared__ float Bs[16 * P];
  int tid = threadIdx.x;
  int n0 = blockIdx.x * 128;
  int m0 = blockIdx.y * 128;
  int tx = tid & 15, ty = tid >> 4;
  int aoff = (ty * 8) + (((ty * 8) >> 5) << 2);
  int boff = (tx * 8) + (((tx * 8) >> 5) << 2);
  float acc[8][8];
#pragma unroll
  for (int ii = 0; ii < 8; ii++)
#pragma unroll
    for (int jj = 0; jj < 8; jj++) acc[ii][jj] = 0.f;

  for (int kc = 0; kc < K; kc += 16) {
    __syncthreads();
#pragma unroll
    for (int l = 0; l < 2; l++) {
      int e = tid + 256 * l;
      int rr = e >> 2, c4 = e & 3;
      int sc = rr + ((rr >> 5) << 2);
      float4 va = *(const float4*)&A[(size_t)(m0 + rr) * K + kc + c4 * 4];
      As[(c4 * 4 + 0) * P + sc] = va.x;
      As[(c4 * 4 + 1) * P + sc] = va.y;
      As[(c4 * 4 + 2) * P + sc] = va.z;
      As[(c4 * 4 + 3) * P + sc] = va.w;
      float4 vb = *(const float4*)&Wc[(size_t)(n0 + rr) * K + kc + c4 * 4];
      Bs[(c4 * 4 + 0) * P + sc] = vb.x;
      Bs[(c4 * 4 + 1) * P + sc] = vb.y;
      Bs[(c4 * 4 + 2) * P + sc] = vb.z;
      Bs[(c4 * 4 + 3) * P + sc] = vb.w;
    }
    __syncthreads();
#pragma unroll 8
    for (int k = 0; k < 16; k++) {
      float4 a0 = *(const float4*)&As[k * P + aoff];
      float4 a1 = *(const float4*)&As[k * P + aoff + 4];
      float4 b0 = *(const float4*)&Bs[k * P + boff];
      float4 b1 = *(const float4*)&Bs[k * P + boff + 4];
      float av[8] = {a0.x, a0.y, a0.z, a0.w, a1.x, a1.y, a1.z, a1.w};
      float bv[8] = {b0.x, b0.y, b0.z, b0.w, b1.x, b1.y, b1.z, b1.w};
#pragma unroll
      for (int ii = 0; ii < 8; ii++)
#pragma unroll
        for (int jj = 0; jj < 8; jj++)
          acc[ii][jj] = fmaf(av[ii], bv[jj], acc[ii][jj]);
    }
  }

  int col0 = n0 + tx * 8;
  float bv[8];
#pragma unroll
  for (int jj = 0; jj < 8; jj++) {
    int col = col0 + jj;
    bv[jj] = (col >= O) ? bias[col - O] : 0.f;
  }
#pragma unroll
  for (int ii = 0; ii < 8; ii++) {
    int row = m0 + ty * 8 + ii;
    float4 o0, o1;
    o0.x = acc[ii][0] + bv[0];
    o0.y = acc[ii][1] + bv[1];
    o0.z = acc[ii][2] + bv[2];
    o0.w = acc[ii][3] + bv[3];
    o1.x = acc[ii][4] + bv[4];
    o1.y = acc[ii][5] + bv[5];
    o1.z = acc[ii][6] + bv[6];
    o1.w = acc[ii][7] + bv[7];
    *(float4*)&Y[(size_t)row * N2 + col0] = o0;
    *(float4*)&Y[(size_t)row * N2 + col0 + 4] = o1;
  }
}

// ---------------- small GEMM for layer 1 (K=3) ----------------
__global__ __launch_bounds__(256) void gemm_k(const float* __restrict__ A,
                                              const float* __restrict__ Wc,
                                              const float* __restrict__ bias,
                                              float* __restrict__ Y, int K, int N2,
                                              int O) {
  __shared__ float As[8 * 68];
  __shared__ float Bs[8 * 68];
  int tid = threadIdx.x;
  int n0 = blockIdx.x * 64;
  int m0 = blockIdx.y * 64;
  int tx = tid & 15, ty = tid >> 4;
  float acc[4][4] = {};
  for (int k0 = 0; k0 < K; k0 += 8) {
    __syncthreads();
    {
      int e = tid, mm = e >> 3, kk = e & 7;
      As[kk * 68 + mm] = (k0 + kk < K) ? A[(size_t)(m0 + mm) * K + k0 + kk] : 0.f;
      int nn = mm;
      Bs[kk * 68 + nn] = (k0 + kk < K) ? Wc[(size_t)(n0 + nn) * K + k0 + kk] : 0.f;
      e = tid + 256;
      mm = e >> 3;
      kk = e & 7;
      As[kk * 68 + mm] = (k0 + kk < K) ? A[(size_t)(m0 + mm) * K + k0 + kk] : 0.f;
      nn = mm;
      Bs[kk * 68 + nn] = (k0 + kk < K) ? Wc[(size_t)(n0 + nn) * K + k0 + kk] : 0.f;
    }
    __syncthreads();
#pragma unroll
    for (int kk = 0; kk < 8; kk++) {
      float4 av = *(float4*)&As[kk * 68 + ty * 4];
      float4 bv = *(float4*)&Bs[kk * 68 + tx * 4];
      float a[4] = {av.x, av.y, av.z, av.w};
      float bb2[4] = {bv.x, bv.y, bv.z, bv.w};
#pragma unroll
      for (int ii = 0; ii < 4; ii++)
#pragma unroll
        for (int jj = 0; jj < 4; jj++) acc[ii][jj] += a[ii] * bb2[jj];
    }
  }
  int col = n0 + tx * 4;
  bool isV = (col >= O);
  float b0 = 0.f, b1 = 0.f, b2 = 0.f, b3 = 0.f;
  if (isV) {
    b0 = bias[col + 0 - O];
    b1 = bias[col + 1 - O];
    b2 = bias[col + 2 - O];
    b3 = bias[col + 3 - O];
  }
#pragma unroll
  for (int ii = 0; ii < 4; ii++) {
    int row = m0 + ty * 4 + ii;
    float4 o4;
    o4.x = acc[ii][0] + b0;
    o4.y = acc[ii][1] + b1;
    o4.z = acc[ii][2] + b2;
    o4.w = acc[ii][3] + b3;
    *(float4*)&Y[(size_t)row * N2 + col] = o4;
  }
}

// ---------------- gather + max + LeakyReLU (float4) ----------------
template <int O>
__global__ __launch_bounds__(256) void gmax_v(const float* __restrict__ Y,
                                              const int* __restrict__ idx,
                                              float* __restrict__ out) {
  constexpr int T = O / 4;
  constexpr int G = 256 / T;
  int tid = threadIdx.x;
  int p = blockIdx.x * G + tid / T;
  int o4 = (tid % T) * 4;
  int b = p >> 12;
  constexpr int N2 = 2 * O;
  const int* ip = idx + (size_t)p * KNN;
  float4 m = make_float4(NEG_INF, NEG_INF, NEG_INF, NEG_INF);
#pragma unroll
  for (int k = 0; k < KNN; k++) {
    int j = ip[k];
    float4 v = *(const float4*)&Y[((size_t)(b * NTOT + j)) * N2 + o4];
    m.x = fmaxf(m.x, v.x);
    m.y = fmaxf(m.y, v.y);
    m.z = fmaxf(m.z, v.z);
    m.w = fmaxf(m.w, v.w);
  }
  float4 c = *(const float4*)&Y[(size_t)p * N2 + O + o4];
  float4 o;
  o.x = c.x + m.x;
  o.y = c.y + m.y;
  o.z = c.z + m.z;
  o.w = c.w + m.w;
  o.x = (o.x >= 0.f) ? o.x : 0.2f * o.x;
  o.y = (o.y >= 0.f) ? o.y : 0.2f * o.y;
  o.z = (o.z >= 0.f) ? o.z : 0.2f * o.z;
  o.w = (o.w >= 0.f) ? o.w : 0.2f * o.w;
  *(float4*)&out[(size_t)p * O + o4] = o;
}

// ---------------- host side ----------------
template <int C, int O>
static void run_layer(const float* fin, void* const* w5, float* fout, float* Wc,
                      float* biasb, int* idx, float* Y, float* sqh,
                      unsigned* cval, ushort* Xhi, ushort* Xlo,
                      hipStream_t stream) {
  const float* W = (const float*)w5[0];
  const float* g = (const float*)w5[1];
  const float* bb = (const float*)w5[2];
  const float* mm = (const float*)w5[3];
  const float* vv = (const float*)w5[4];
  int N2 = 2 * O;
  prep_w<<<(2 * O * C + 255) / 256, 256, 0, stream>>>(W, g, bb, mm, vv, Wc, biasb, O, C);
  if (C == 3) {
    knn3_g<<<NBATCH * 64 * JSPLIT3, 256, 0, stream>>>(fin, cval);
    kref_w<3, 256><<<NBATCH * NTOT / 4, 256, 0, stream>>>(fin, cval, idx);
    dim3 gg(N2 / 64, NBATCH * NTOT / 64);
    gemm_k<<<gg, 256, 0, stream>>>(fin, Wc, biasb, Y, C, N2, O);
  } else {
    constexpr int CC = (C == 3) ? 64 : C;
    cvt_k<<<NBATCH * NTOT * CC / 256, 256, 0, stream>>>(fin, Xhi, Xlo);
    sqh_k<CC><<<NBATCH * NTOT / 256, 256, 0, stream>>>(fin, sqh);
    knn_m<CC><<<NBATCH * 32 * JSPLIT, 256, 0, stream>>>(Xhi, Xlo, sqh, cval);
    kref_w<CC, 256><<<NBATCH * NTOT / 4, 256, 0, stream>>>(fin, cval, idx);
    dim3 gg(N2 / 128, NBATCH * NTOT / 128);
    gemm128<<<gg, 256, 0, stream>>>(fin, Wc, biasb, Y, C, N2, O);
  }
  gmax_v<O><<<NBATCH * NTOT / (256 / (O / 4)), 256, 0, stream>>>(Y, idx, fout);
}

extern "C" void kernel_launch(void* const* d_in, const int* in_sizes, int n_in,
                              void* d_out, int out_size, void* d_ws, size_t ws_size,
                              hipStream_t stream) {
  const float* x = (const float*)d_in[0];
  char* ws = (char*)d_ws;
  float* Wc = (float*)(ws + 0);            // 262144
  float* biasb = (float*)(ws + 262144);    // 1024
  int* idx = (int*)(ws + 263168);          // 1310720
  float* sqh = (float*)(ws + 1573888);     // 65536
  float* Y = (float*)(ws + 1639424);       // 33554432 -> ends 35193856
  float* x1 = (float*)(ws + 35193856);     // 4194304
  float* x2 = (float*)(ws + 39388160);     // 4194304
  float* x3 = (float*)(ws + 43582464);     // 8388608

  // aliases inside Y (all consumed by kref_w before gemm writes Y):
  unsigned* cval = (unsigned*)Y;                           // 16384*256*4 = 16777216
  ushort* Xhi = (ushort*)((char*)Y + 16777216);            // 4194304
  ushort* Xlo = (ushort*)((char*)Y + 16777216 + 4194304);  // 4194304

  float* outf = (float*)d_out;

  run_layer<3, 64>(x, d_in + 1, x1, Wc, biasb, idx, Y, sqh, cval, Xhi, Xlo, stream);
  run_layer<64, 64>(x1, d_in + 6, x2, Wc, biasb, idx, Y, sqh, cval, Xhi, Xlo, stream);
  run_layer<64, 128>(x2, d_in + 11, x3, Wc, biasb, idx, Y, sqh, cval, Xhi, Xlo, stream);
  run_layer<128, 256>(x3, d_in + 16, outf, Wc, biasb, idx, Y, sqh, cval, Xhi, Xlo, stream);
}

// Round 2
// 1109.466 us; speedup vs baseline: 1.0321x; 1.0321x over previous
//
#include <hip/hip_runtime.h>

#define NTOT 4096
#define NBATCH 4
#define KNN 20
#define JSPLIT 8
#define JSPLIT3 4
#define KSUB 16
#define KMRG 28
#define CSLOT 256  // per-point candidate slot (256 entries, filled by both paths)

constexpr float NEG_INF = -3.0e38f;

typedef __attribute__((ext_vector_type(8))) short bf16x8;
typedef __attribute__((ext_vector_type(4))) float f32x4;

__device__ __forceinline__ unsigned pk(float f, int j) {
  unsigned u = __float_as_uint(f);
  u = (u & 0x80000000u) ? ~u : (u | 0x80000000u);
  return (u & 0xFFFFF000u) | (unsigned)j;
}

__device__ __forceinline__ void pins16(unsigned u, unsigned (&tv)[KSUB]) {
  if (u > tv[0]) {
    tv[0] = u;
#pragma unroll
    for (int x = 1; x < KSUB; x++) {
      unsigned mn = min(tv[0], tv[x]);
      unsigned mx = max(tv[0], tv[x]);
      tv[0] = mn;
      tv[x] = mx;
    }
  }
}

// ---------------- prep: fold BN scale into weights ----------------
__global__ void prep_w(const float* __restrict__ W, const float* __restrict__ gg,
                       const float* __restrict__ bb, const float* __restrict__ mm,
                       const float* __restrict__ vv, float* __restrict__ Wc,
                       float* __restrict__ bias, int O, int C) {
  int t = blockIdx.x * 256 + threadIdx.x;
  if (t >= 2 * O * C) return;
  int o2 = t / C, c = t - o2 * C;
  int o = (o2 < O) ? o2 : o2 - O;
  float s = gg[o] * rsqrtf(vv[o] + 1e-5f);
  float w = (o2 < O) ? W[o * 2 * C + c] * s
                     : (W[o * 2 * C + C + c] - W[o * 2 * C + c]) * s;
  Wc[o2 * C + c] = w;
  if (o2 >= O && c == 0) bias[o] = bb[o] - mm[o] * s;
}

// ---------------- split-bf16 conversion: x = hi + lo ----------------
__global__ void cvt_k(const float* __restrict__ f, ushort* __restrict__ hi,
                      ushort* __restrict__ lo) {
  int p = blockIdx.x * 256 + threadIdx.x;
  float x = f[p];
  unsigned u = __float_as_uint(x);
  unsigned h = (u + 0x7FFFu + ((u >> 16) & 1u)) >> 16;
  float hf = __uint_as_float(h << 16);
  float r = x - hf;
  unsigned v = __float_as_uint(r);
  unsigned l = (v + 0x7FFFu + ((v >> 16) & 1u)) >> 16;
  hi[p] = (ushort)h;
  lo[p] = (ushort)l;
}

// ---------------- half squared norms (exact fp32) ----------------
template <int C>
__global__ void sqh_k(const float* __restrict__ f, float* __restrict__ sqh) {
  int p = blockIdx.x * 256 + threadIdx.x;
  const float* r = f + (size_t)p * C;
  float s = 0.f;
#pragma unroll
  for (int c4 = 0; c4 < C / 4; c4++) {
    float4 v = *(const float4*)&r[c4 * 4];
    s += v.x * v.x + v.y * v.y + v.z * v.z + v.w * v.w;
  }
  sqh[p] = 0.5f * s;
}

// ---------------- KNN C=3 stage 1: 4-way j-split, 16 sub-lists/row ----------
// Grid NBATCH*64*4 = 1024 blocks (4 blocks/CU). Each block: 64 rows x j-range
// of 1024. Sub-list id = js*4+q -> 16 lists x 16 = 256 = CSLOT exactly.
__global__ __launch_bounds__(256) void knn3_g(const float* __restrict__ feat,
                                              unsigned* __restrict__ cval) {
  __shared__ __align__(16) float sA[64 * 4];

  int tid = threadIdx.x;
  int js = blockIdx.x & (JSPLIT3 - 1);
  int rb = (blockIdx.x >> 2) & 63;
  int b = blockIdx.x >> 8;
  int row0 = rb * 64;
  int r = tid >> 2, q = tid & 3;
  int i = row0 + r;
  const float* fb = feat + (size_t)b * NTOT * 3;

  float c0 = fb[(size_t)i * 3 + 0];
  float c1 = fb[(size_t)i * 3 + 1];
  float c2 = fb[(size_t)i * 3 + 2];

  unsigned tv[KSUB];
#pragma unroll
  for (int t = 0; t < KSUB; t++) tv[t] = 0u;

  for (int jt = js * (NTOT / JSPLIT3); jt < (js + 1) * (NTOT / JSPLIT3); jt += 64) {
    __syncthreads();
    if (tid < 64) {
      sA[tid * 4 + 0] = fb[(size_t)(jt + tid) * 3 + 0];
      sA[tid * 4 + 1] = fb[(size_t)(jt + tid) * 3 + 1];
      sA[tid * 4 + 2] = fb[(size_t)(jt + tid) * 3 + 2];
    }
    __syncthreads();

#pragma unroll
    for (int cc = 0; cc < 4; cc++) {
      float vq[4];
#pragma unroll
      for (int u = 0; u < 4; u++) {
        int jl = (cc * 4 + u) * 4 + q;
        float d0 = c0 - sA[jl * 4];
        float d1 = c1 - sA[jl * 4 + 1];
        float d2 = c2 - sA[jl * 4 + 2];
        vq[u] = -(d0 * d0 + d1 * d1 + d2 * d2);
      }
      float m4 = fmaxf(fmaxf(vq[0], vq[1]), fmaxf(vq[2], vq[3]));
      if (pk(m4, 0xFFF) > tv[0]) {
#pragma unroll
        for (int u = 0; u < 4; u++)
          pins16(pk(vq[u], jt + (cc * 4 + u) * 4 + q), tv);
      }
    }
  }

  int p = b * NTOT + row0 + r;
  int sub = js * 4 + q;  // 0..15
  unsigned* dst = cval + (size_t)p * CSLOT + sub * 16;
#pragma unroll
  for (int t4 = 0; t4 < 4; t4++) {
    uint4 o;
    o.x = tv[t4 * 4 + 0];
    o.y = tv[t4 * 4 + 1];
    o.z = tv[t4 * 4 + 2];
    o.w = tv[t4 * 4 + 3];
    *(uint4*)&dst[t4 * 4] = o;
  }
}

// ---------------- KNN stage 1 (C=64/128): split-bf16 MFMA dot ----------
// LDS: staging (Ah/Al/Bh/Bl, 40960B) OVERLAID with Dt (34816B) -> 40960B
// total => 4 blocks/CU. sqB in registers.
// blockIdx swizzle: low 3 bits = [b(2)|it0(1)] -> each XCD (bid%8) holds ONE
// batch and 16 it-tiles: A working set 2MB + B working set 2MB = 4MB = L2,
// and each B j-slice is shared by 16 co-resident it-blocks (L2 hits).
template <int C>
__global__ __launch_bounds__(256, 4) void knn_m(const ushort* __restrict__ Xhi,
                                                const ushort* __restrict__ Xlo,
                                                const float* __restrict__ sqh,
                                                unsigned* __restrict__ cval) {
  constexpr int RS = 40;  // LDS row stride (bf16): 32 data + 8 pad
  __shared__ __align__(16) char smem[4 * 128 * RS * sizeof(ushort)];  // 40960
  ushort* Ah = (ushort*)smem;
  ushort* Al = Ah + 128 * RS;
  ushort* Bh = Al + 128 * RS;
  ushort* Bl = Bh + 128 * RS;
  float* Dt = (float*)smem;  // 128*68 floats = 34816B, live only post-MFMA

  int tid = threadIdx.x;
  int raw = blockIdx.x;
  int b = raw & 3;
  int js = (raw >> 3) & (JSPLIT - 1);
  int it = (((raw >> 6) & 15) << 1) | ((raw >> 2) & 1);
  int i0 = it * 128;
  const ushort* xh = Xhi + (size_t)b * NTOT * C;
  const ushort* xl = Xlo + (size_t)b * NTOT * C;

  int l = tid & 63, wid = tid >> 6;
  int wi = wid & 1, wj = wid >> 1;
  int n = l & 15, quad = l >> 4;
  // Dt-read ownership: lanes 0..7 hit 8 distinct bank windows (stride 68
  // => window = row&7), so consecutive-lane phase groups are conflict-free.
  int selr = (wid << 5) | (l & 31);  // row 0..127 (bijective over block)
  int sels = l >> 5;                 // which 32-col half

  unsigned tv[KSUB];
#pragma unroll
  for (int t = 0; t < KSUB; t++) tv[t] = 0u;

  for (int jt = 0; jt < NTOT / (128 * JSPLIT); jt++) {
    int j0 = js * (NTOT / JSPLIT) + jt * 128;

    // per-thread -|xj|^2/2 values for this wave's j-columns (replaces sqB LDS)
    float sqv[4];
#pragma unroll
    for (int tj = 0; tj < 4; tj++)
      sqv[tj] = sqh[b * NTOT + j0 + wj * 64 + tj * 16 + n];

    f32x4 acc[4][4];
#pragma unroll
    for (int ti = 0; ti < 4; ti++)
#pragma unroll
      for (int tj = 0; tj < 4; tj++) acc[ti][tj] = (f32x4)(0.f);

    for (int kc = 0; kc < C; kc += 32) {
      __syncthreads();
#pragma unroll
      for (int l2 = 0; l2 < 2; l2++) {
        int e = tid + 256 * l2;
        int rr = e >> 2, ko = (e & 3) * 8;
        *(uint4*)&Ah[rr * RS + ko] = *(const uint4*)&xh[(size_t)(i0 + rr) * C + kc + ko];
        *(uint4*)&Al[rr * RS + ko] = *(const uint4*)&xl[(size_t)(i0 + rr) * C + kc + ko];
        *(uint4*)&Bh[rr * RS + ko] = *(const uint4*)&xh[(size_t)(j0 + rr) * C + kc + ko];
        *(uint4*)&Bl[rr * RS + ko] = *(const uint4*)&xl[(size_t)(j0 + rr) * C + kc + ko];
      }
      __syncthreads();

      bf16x8 ah[4], al[4];
#pragma unroll
      for (int ti = 0; ti < 4; ti++) {
        int row = wi * 64 + ti * 16 + n;
        ah[ti] = *(const bf16x8*)&Ah[row * RS + quad * 8];
        al[ti] = *(const bf16x8*)&Al[row * RS + quad * 8];
      }
#pragma unroll
      for (int tj = 0; tj < 4; tj++) {
        int row = wj * 64 + tj * 16 + n;
        bf16x8 bh = *(const bf16x8*)&Bh[row * RS + quad * 8];
        bf16x8 bl = *(const bf16x8*)&Bl[row * RS + quad * 8];
#pragma unroll
        for (int ti = 0; ti < 4; ti++) {
          acc[ti][tj] = __builtin_amdgcn_mfma_f32_16x16x32_bf16(ah[ti], bh, acc[ti][tj], 0, 0, 0);
          acc[ti][tj] = __builtin_amdgcn_mfma_f32_16x16x32_bf16(ah[ti], bl, acc[ti][tj], 0, 0, 0);
          acc[ti][tj] = __builtin_amdgcn_mfma_f32_16x16x32_bf16(al[ti], bh, acc[ti][tj], 0, 0, 0);
        }
      }
    }
    // all fragment reads done before Dt overwrites the staging buffers
    __syncthreads();

    // phase A: waves wj==0 hold j-cols 0..63
    if (wj == 0) {
#pragma unroll
      for (int ti = 0; ti < 4; ti++)
#pragma unroll
        for (int tj = 0; tj < 4; tj++) {
          float q = sqv[tj];
#pragma unroll
          for (int r = 0; r < 4; r++)
            Dt[(wi * 64 + ti * 16 + quad * 4 + r) * 68 + tj * 16 + n] =
                acc[ti][tj][r] - q;
        }
    }
    __syncthreads();
#pragma unroll
    for (int t4 = 0; t4 < 8; t4++) {
      float4 v = *(const float4*)&Dt[selr * 68 + sels * 32 + t4 * 4];
      float m4 = fmaxf(fmaxf(v.x, v.y), fmaxf(v.z, v.w));
      if (pk(m4, 0xFFF) > tv[0]) {
        int jb = j0 + sels * 32 + t4 * 4;
        pins16(pk(v.x, jb + 0), tv);
        pins16(pk(v.y, jb + 1), tv);
        pins16(pk(v.z, jb + 2), tv);
        pins16(pk(v.w, jb + 3), tv);
      }
    }
    __syncthreads();
    // phase B: waves wj==1 hold j-cols 64..127
    if (wj == 1) {
#pragma unroll
      for (int ti = 0; ti < 4; ti++)
#pragma unroll
        for (int tj = 0; tj < 4; tj++) {
          float q = sqv[tj];
#pragma unroll
          for (int r = 0; r < 4; r++)
            Dt[(wi * 64 + ti * 16 + quad * 4 + r) * 68 + tj * 16 + n] =
                acc[ti][tj][r] - q;
        }
    }
    __syncthreads();
#pragma unroll
    for (int t4 = 0; t4 < 8; t4++) {
      float4 v = *(const float4*)&Dt[selr * 68 + sels * 32 + t4 * 4];
      float m4 = fmaxf(fmaxf(v.x, v.y), fmaxf(v.z, v.w));
      if (pk(m4, 0xFFF) > tv[0]) {
        int jb = j0 + 64 + sels * 32 + t4 * 4;
        pins16(pk(v.x, jb + 0), tv);
        pins16(pk(v.y, jb + 1), tv);
        pins16(pk(v.z, jb + 2), tv);
        pins16(pk(v.w, jb + 3), tv);
      }
    }
    // next iteration's kc-loop barrier protects Dt reads vs restaging
  }

  int p = b * NTOT + i0 + selr;
  int sub = js * 2 + sels;  // 0..15
  unsigned* dst = cval + (size_t)p * CSLOT + sub * 16;
#pragma unroll
  for (int t4 = 0; t4 < 4; t4++) {
    uint4 o;
    o.x = tv[t4 * 4 + 0];
    o.y = tv[t4 * 4 + 1];
    o.z = tv[t4 * 4 + 2];
    o.w = tv[t4 * 4 + 3];
    *(uint4*)&dst[t4 * 4] = o;
  }
}

// ---------------- wave-per-point merge + exact refine ----------------
template <int C, int NC>
__global__ __launch_bounds__(256) void kref_w(const float* __restrict__ feat,
                                              const unsigned* __restrict__ cval,
                                              int* __restrict__ outidx) {
  int tid = threadIdx.x;
  int lane = tid & 63;
  int p = blockIdx.x * 4 + (tid >> 6);
  int b = p >> 12;
  int i = p & (NTOT - 1);
  const float* fb = feat + (size_t)b * NTOT * C;

  unsigned c0 = 0, c1 = 0, c2 = 0, c3 = 0;
  if (NC == 256) {
    uint4 cc = *(const uint4*)&cval[(size_t)p * CSLOT + lane * 4];
    c0 = cc.x;
    c1 = cc.y;
    c2 = cc.z;
    c3 = cc.w;
  } else {
    c0 = cval[(size_t)p * CSLOT + lane];
  }

  int jl[KMRG];
  int myj = -1;
#pragma unroll
  for (int t = 0; t < KMRG; t++) {
    unsigned m = max(max(c0, c1), max(c2, c3));
#pragma unroll
    for (int s = 1; s < 64; s <<= 1) m = max(m, (unsigned)__shfl_xor((int)m, s));
    jl[t] = (int)(m & 0xFFFu);
    if (lane == t) myj = (int)(m & 0xFFFu);
    if (c0 == m) c0 = 0;
    if (c1 == m) c1 = 0;
    if (c2 == m) c2 = 0;
    if (c3 == m) c3 = 0;
  }

  float myval = NEG_INF;
  if (C == 3) {
    if (lane < KMRG) {
      float x0 = fb[(size_t)i * 3 + 0];
      float x1 = fb[(size_t)i * 3 + 1];
      float x2 = fb[(size_t)i * 3 + 2];
      float y0 = fb[(size_t)myj * 3 + 0];
      float y1 = fb[(size_t)myj * 3 + 1];
      float y2 = fb[(size_t)myj * 3 + 2];
      float d0 = x0 - y0, d1 = x1 - y1, d2 = x2 - y2;
      myval = -(d0 * d0 + d1 * d1 + d2 * d2);
    }
  } else {
    constexpr int CPL = (C >= 64) ? C / 64 : 1;  // floats per lane
    float fx0, fx1 = 0.f;
    if (CPL == 2) {
      float2 xv = *(const float2*)&fb[(size_t)i * C + lane * 2];
      fx0 = xv.x;
      fx1 = xv.y;
    } else {
      fx0 = fb[(size_t)i * C + lane];
    }
#pragma unroll
    for (int u = 0; u < KMRG; u++) {
      int j = jl[u];
      float d;
      if (CPL == 2) {
        float2 yv = *(const float2*)&fb[(size_t)j * C + lane * 2];
        float dx = fx0 - yv.x, dy = fx1 - yv.y;
        d = dx * dx + dy * dy;
      } else {
        float y = fb[(size_t)j * C + lane];
        float dx = fx0 - y;
        d = dx * dx;
      }
#pragma unroll
      for (int s = 1; s < 64; s <<= 1) d += __shfl_xor(d, s);
      if (lane == u) myval = -d;
    }
  }

  // final exact top-20 across lanes (lane u holds candidate u)
  int wj = 0;
#pragma unroll
  for (int t = 0; t < KNN; t++) {
    float bv = myval;
    int bx = myj;
#pragma unroll
    for (int s = 1; s < 64; s <<= 1) {
      float ov = __shfl_xor(bv, s);
      int ox = __shfl_xor(bx, s);
      if (ov > bv || (ov == bv && ox < bx)) {
        bv = ov;
        bx = ox;
      }
    }
    if (lane == t) wj = bx;
    if (myj == bx) myval = NEG_INF;
  }
  if (lane < KNN) outidx[(size_t)p * KNN + lane] = wj;
}

// ---------------- 128x128 GEMM (K>=16): Y = A * Wc^T (+bias on V half) ------
__global__ __launch_bounds__(256) void gemm128(const float* __restrict__ A,
                                               const float* __restrict__ Wc,
                                               const float* __restrict__ bias,
                                               float* __restrict__ Y, int K, int N2,
                                               int O) {
  constexpr int P = 140;
  __shared__ float As[16 * P];
  __shared__ float Bs[16 * P];
  int tid = threadIdx.x;
  int n0 = blockIdx.x * 128;
  int m0 = blockIdx.y * 128;
  int tx = tid & 15, ty = tid >> 4;
  int aoff = (ty * 8) + (((ty * 8) >> 5) << 2);
  int boff = (tx * 8) + (((tx * 8) >> 5) << 2);
  float acc[8][8];
#pragma unroll
  for (int ii = 0; ii < 8; ii++)
#pragma unroll
    for (int jj = 0; jj < 8; jj++) acc[ii][jj] = 0.f;

  for (int kc = 0; kc < K; kc += 16) {
    __syncthreads();
#pragma unroll
    for (int l = 0; l < 2; l++) {
      int e = tid + 256 * l;
      int rr = e >> 2, c4 = e & 3;
      int sc = rr + ((rr >> 5) << 2);
      float4 va = *(const float4*)&A[(size_t)(m0 + rr) * K + kc + c4 * 4];
      As[(c4 * 4 + 0) * P + sc] = va.x;
      As[(c4 * 4 + 1) * P + sc] = va.y;
      As[(c4 * 4 + 2) * P + sc] = va.z;
      As[(c4 * 4 + 3) * P + sc] = va.w;
      float4 vb = *(const float4*)&Wc[(size_t)(n0 + rr) * K + kc + c4 * 4];
      Bs[(c4 * 4 + 0) * P + sc] = vb.x;
      Bs[(c4 * 4 + 1) * P + sc] = vb.y;
      Bs[(c4 * 4 + 2) * P + sc] = vb.z;
      Bs[(c4 * 4 + 3) * P + sc] = vb.w;
    }
    __syncthreads();
#pragma unroll 8
    for (int k = 0; k < 16; k++) {
      float4 a0 = *(const float4*)&As[k * P + aoff];
      float4 a1 = *(const float4*)&As[k * P + aoff + 4];
      float4 b0 = *(const float4*)&Bs[k * P + boff];
      float4 b1 = *(const float4*)&Bs[k * P + boff + 4];
      float av[8] = {a0.x, a0.y, a0.z, a0.w, a1.x, a1.y, a1.z, a1.w};
      float bv[8] = {b0.x, b0.y, b0.z, b0.w, b1.x, b1.y, b1.z, b1.w};
#pragma unroll
      for (int ii = 0; ii < 8; ii++)
#pragma unroll
        for (int jj = 0; jj < 8; jj++)
          acc[ii][jj] = fmaf(av[ii], bv[jj], acc[ii][jj]);
    }
  }

  int col0 = n0 + tx * 8;
  float bv[8];
#pragma unroll
  for (int jj = 0; jj < 8; jj++) {
    int col = col0 + jj;
    bv[jj] = (col >= O) ? bias[col - O] : 0.f;
  }
#pragma unroll
  for (int ii = 0; ii < 8; ii++) {
    int row = m0 + ty * 8 + ii;
    float4 o0, o1;
    o0.x = acc[ii][0] + bv[0];
    o0.y = acc[ii][1] + bv[1];
    o0.z = acc[ii][2] + bv[2];
    o0.w = acc[ii][3] + bv[3];
    o1.x = acc[ii][4] + bv[4];
    o1.y = acc[ii][5] + bv[5];
    o1.z = acc[ii][6] + bv[6];
    o1.w = acc[ii][7] + bv[7];
    *(float4*)&Y[(size_t)row * N2 + col0] = o0;
    *(float4*)&Y[(size_t)row * N2 + col0 + 4] = o1;
  }
}

// ---------------- small GEMM for layer 1 (K=3) ----------------
__global__ __launch_bounds__(256) void gemm_k(const float* __restrict__ A,
                                              const float* __restrict__ Wc,
                                              const float* __restrict__ bias,
                                              float* __restrict__ Y, int K, int N2,
                                              int O) {
  __shared__ float As[8 * 68];
  __shared__ float Bs[8 * 68];
  int tid = threadIdx.x;
  int n0 = blockIdx.x * 64;
  int m0 = blockIdx.y * 64;
  int tx = tid & 15, ty = tid >> 4;
  float acc[4][4] = {};
  for (int k0 = 0; k0 < K; k0 += 8) {
    __syncthreads();
    {
      int e = tid, mm = e >> 3, kk = e & 7;
      As[kk * 68 + mm] = (k0 + kk < K) ? A[(size_t)(m0 + mm) * K + k0 + kk] : 0.f;
      int nn = mm;
      Bs[kk * 68 + nn] = (k0 + kk < K) ? Wc[(size_t)(n0 + nn) * K + k0 + kk] : 0.f;
      e = tid + 256;
      mm = e >> 3;
      kk = e & 7;
      As[kk * 68 + mm] = (k0 + kk < K) ? A[(size_t)(m0 + mm) * K + k0 + kk] : 0.f;
      nn = mm;
      Bs[kk * 68 + nn] = (k0 + kk < K) ? Wc[(size_t)(n0 + nn) * K + k0 + kk] : 0.f;
    }
    __syncthreads();
#pragma unroll
    for (int kk = 0; kk < 8; kk++) {
      float4 av = *(float4*)&As[kk * 68 + ty * 4];
      float4 bv = *(float4*)&Bs[kk * 68 + tx * 4];
      float a[4] = {av.x, av.y, av.z, av.w};
      float bb2[4] = {bv.x, bv.y, bv.z, bv.w};
#pragma unroll
      for (int ii = 0; ii < 4; ii++)
#pragma unroll
        for (int jj = 0; jj < 4; jj++) acc[ii][jj] += a[ii] * bb2[jj];
    }
  }
  int col = n0 + tx * 4;
  bool isV = (col >= O);
  float b0 = 0.f, b1 = 0.f, b2 = 0.f, b3 = 0.f;
  if (isV) {
    b0 = bias[col + 0 - O];
    b1 = bias[col + 1 - O];
    b2 = bias[col + 2 - O];
    b3 = bias[col + 3 - O];
  }
#pragma unroll
  for (int ii = 0; ii < 4; ii++) {
    int row = m0 + ty * 4 + ii;
    float4 o4;
    o4.x = acc[ii][0] + b0;
    o4.y = acc[ii][1] + b1;
    o4.z = acc[ii][2] + b2;
    o4.w = acc[ii][3] + b3;
    *(float4*)&Y[(size_t)row * N2 + col] = o4;
  }
}

// ---------------- gather + max + LeakyReLU (float4) ----------------
template <int O>
__global__ __launch_bounds__(256) void gmax_v(const float* __restrict__ Y,
                                              const int* __restrict__ idx,
                                              float* __restrict__ out) {
  constexpr int T = O / 4;
  constexpr int G = 256 / T;
  int tid = threadIdx.x;
  int p = blockIdx.x * G + tid / T;
  int o4 = (tid % T) * 4;
  int b = p >> 12;
  constexpr int N2 = 2 * O;
  const int* ip = idx + (size_t)p * KNN;
  float4 m = make_float4(NEG_INF, NEG_INF, NEG_INF, NEG_INF);
#pragma unroll
  for (int k = 0; k < KNN; k++) {
    int j = ip[k];
    float4 v = *(const float4*)&Y[((size_t)(b * NTOT + j)) * N2 + o4];
    m.x = fmaxf(m.x, v.x);
    m.y = fmaxf(m.y, v.y);
    m.z = fmaxf(m.z, v.z);
    m.w = fmaxf(m.w, v.w);
  }
  float4 c = *(const float4*)&Y[(size_t)p * N2 + O + o4];
  float4 o;
  o.x = c.x + m.x;
  o.y = c.y + m.y;
  o.z = c.z + m.z;
  o.w = c.w + m.w;
  o.x = (o.x >= 0.f) ? o.x : 0.2f * o.x;
  o.y = (o.y >= 0.f) ? o.y : 0.2f * o.y;
  o.z = (o.z >= 0.f) ? o.z : 0.2f * o.z;
  o.w = (o.w >= 0.f) ? o.w : 0.2f * o.w;
  *(float4*)&out[(size_t)p * O + o4] = o;
}

// ---------------- host side ----------------
template <int C, int O>
static void run_layer(const float* fin, void* const* w5, float* fout, float* Wc,
                      float* biasb, int* idx, float* Y, float* sqh,
                      unsigned* cval, ushort* Xhi, ushort* Xlo,
                      hipStream_t stream) {
  const float* W = (const float*)w5[0];
  const float* g = (const float*)w5[1];
  const float* bb = (const float*)w5[2];
  const float* mm = (const float*)w5[3];
  const float* vv = (const float*)w5[4];
  int N2 = 2 * O;
  prep_w<<<(2 * O * C + 255) / 256, 256, 0, stream>>>(W, g, bb, mm, vv, Wc, biasb, O, C);
  if (C == 3) {
    knn3_g<<<NBATCH * 64 * JSPLIT3, 256, 0, stream>>>(fin, cval);
    kref_w<3, 256><<<NBATCH * NTOT / 4, 256, 0, stream>>>(fin, cval, idx);
    dim3 gg(N2 / 64, NBATCH * NTOT / 64);
    gemm_k<<<gg, 256, 0, stream>>>(fin, Wc, biasb, Y, C, N2, O);
  } else {
    constexpr int CC = (C == 3) ? 64 : C;
    cvt_k<<<NBATCH * NTOT * CC / 256, 256, 0, stream>>>(fin, Xhi, Xlo);
    sqh_k<CC><<<NBATCH * NTOT / 256, 256, 0, stream>>>(fin, sqh);
    knn_m<CC><<<NBATCH * 32 * JSPLIT, 256, 0, stream>>>(Xhi, Xlo, sqh, cval);
    kref_w<CC, 256><<<NBATCH * NTOT / 4, 256, 0, stream>>>(fin, cval, idx);
    dim3 gg(N2 / 128, NBATCH * NTOT / 128);
    gemm128<<<gg, 256, 0, stream>>>(fin, Wc, biasb, Y, C, N2, O);
  }
  gmax_v<O><<<NBATCH * NTOT / (256 / (O / 4)), 256, 0, stream>>>(Y, idx, fout);
}

extern "C" void kernel_launch(void* const* d_in, const int* in_sizes, int n_in,
                              void* d_out, int out_size, void* d_ws, size_t ws_size,
                              hipStream_t stream) {
  const float* x = (const float*)d_in[0];
  char* ws = (char*)d_ws;
  float* Wc = (float*)(ws + 0);            // 262144
  float* biasb = (float*)(ws + 262144);    // 1024
  int* idx = (int*)(ws + 263168);          // 1310720
  float* sqh = (float*)(ws + 1573888);     // 65536
  float* Y = (float*)(ws + 1639424);       // 33554432 -> ends 35193856
  float* x1 = (float*)(ws + 35193856);     // 4194304
  float* x2 = (float*)(ws + 39388160);     // 4194304
  float* x3 = (float*)(ws + 43582464);     // 8388608

  // aliases inside Y (all consumed by kref_w before gemm writes Y):
  unsigned* cval = (unsigned*)Y;                           // 16384*256*4 = 16777216
  ushort* Xhi = (ushort*)((char*)Y + 16777216);            // 4194304
  ushort* Xlo = (ushort*)((char*)Y + 16777216 + 4194304);  // 4194304

  float* outf = (float*)d_out;

  run_layer<3, 64>(x, d_in + 1, x1, Wc, biasb, idx, Y, sqh, cval, Xhi, Xlo, stream);
  run_layer<64, 64>(x1, d_in + 6, x2, Wc, biasb, idx, Y, sqh, cval, Xhi, Xlo, stream);
  run_layer<64, 128>(x2, d_in + 11, x3, Wc, biasb, idx, Y, sqh, cval, Xhi, Xlo, stream);
  run_layer<128, 256>(x3, d_in + 16, outf, Wc, biasb, idx, Y, sqh, cval, Xhi, Xlo, stream);
}

// Round 3
// 1058.309 us; speedup vs baseline: 1.0820x; 1.0483x over previous
//
#include <hip/hip_runtime.h>

#define NTOT 4096
#define NBATCH 4
#define KNN 20
#define JSPLIT 8
#define JSPLIT3 4
#define KSUB 16
#define KMRG 28
#define CSLOT 256  // per-point candidate slot (256 entries, filled by both paths)

constexpr float NEG_INF = -3.0e38f;

typedef __attribute__((ext_vector_type(8))) short bf16x8;
typedef __attribute__((ext_vector_type(4))) float f32x4;

__device__ __forceinline__ unsigned pk(float f, int j) {
  unsigned u = __float_as_uint(f);
  u = (u & 0x80000000u) ? ~u : (u | 0x80000000u);
  return (u & 0xFFFFF000u) | (unsigned)j;
}

__device__ __forceinline__ void pins16(unsigned u, unsigned (&tv)[KSUB]) {
  if (u > tv[0]) {
    tv[0] = u;
#pragma unroll
    for (int x = 1; x < KSUB; x++) {
      unsigned mn = min(tv[0], tv[x]);
      unsigned mx = max(tv[0], tv[x]);
      tv[0] = mn;
      tv[x] = mx;
    }
  }
}

// async global->LDS 16B copy (lane i writes lds + i*16)
__device__ __forceinline__ void gll16(const void* g, void* l) {
  __builtin_amdgcn_global_load_lds(
      (const __attribute__((address_space(1))) unsigned int*)g,
      (__attribute__((address_space(3))) unsigned int*)l, 16, 0, 0);
}

// ---------------- prep: fold BN scale into weights ----------------
__global__ void prep_w(const float* __restrict__ W, const float* __restrict__ gg,
                       const float* __restrict__ bb, const float* __restrict__ mm,
                       const float* __restrict__ vv, float* __restrict__ Wc,
                       float* __restrict__ bias, int O, int C) {
  int t = blockIdx.x * 256 + threadIdx.x;
  if (t >= 2 * O * C) return;
  int o2 = t / C, c = t - o2 * C;
  int o = (o2 < O) ? o2 : o2 - O;
  float s = gg[o] * rsqrtf(vv[o] + 1e-5f);
  float w = (o2 < O) ? W[o * 2 * C + c] * s
                     : (W[o * 2 * C + C + c] - W[o * 2 * C + c]) * s;
  Wc[o2 * C + c] = w;
  if (o2 >= O && c == 0) bias[o] = bb[o] - mm[o] * s;
}

// ---------------- split-bf16 conversion: x = hi + lo ----------------
__global__ void cvt_k(const float* __restrict__ f, ushort* __restrict__ hi,
                      ushort* __restrict__ lo) {
  int p = blockIdx.x * 256 + threadIdx.x;
  float x = f[p];
  unsigned u = __float_as_uint(x);
  unsigned h = (u + 0x7FFFu + ((u >> 16) & 1u)) >> 16;
  float hf = __uint_as_float(h << 16);
  float r = x - hf;
  unsigned v = __float_as_uint(r);
  unsigned l = (v + 0x7FFFu + ((v >> 16) & 1u)) >> 16;
  hi[p] = (ushort)h;
  lo[p] = (ushort)l;
}

// ---------------- half squared norms (exact fp32) ----------------
template <int C>
__global__ void sqh_k(const float* __restrict__ f, float* __restrict__ sqh) {
  int p = blockIdx.x * 256 + threadIdx.x;
  const float* r = f + (size_t)p * C;
  float s = 0.f;
#pragma unroll
  for (int c4 = 0; c4 < C / 4; c4++) {
    float4 v = *(const float4*)&r[c4 * 4];
    s += v.x * v.x + v.y * v.y + v.z * v.z + v.w * v.w;
  }
  sqh[p] = 0.5f * s;
}

// ---------------- KNN C=3 stage 1 ----------
__global__ __launch_bounds__(256) void knn3_g(const float* __restrict__ feat,
                                              unsigned* __restrict__ cval) {
  __shared__ __align__(16) float sA[64 * 4];

  int tid = threadIdx.x;
  int js = blockIdx.x & (JSPLIT3 - 1);
  int rb = (blockIdx.x >> 2) & 63;
  int b = blockIdx.x >> 8;
  int row0 = rb * 64;
  int r = tid >> 2, q = tid & 3;
  int i = row0 + r;
  const float* fb = feat + (size_t)b * NTOT * 3;

  float c0 = fb[(size_t)i * 3 + 0];
  float c1 = fb[(size_t)i * 3 + 1];
  float c2 = fb[(size_t)i * 3 + 2];

  unsigned tv[KSUB];
#pragma unroll
  for (int t = 0; t < KSUB; t++) tv[t] = 0u;

  for (int jt = js * (NTOT / JSPLIT3); jt < (js + 1) * (NTOT / JSPLIT3); jt += 64) {
    __syncthreads();
    if (tid < 64) {
      sA[tid * 4 + 0] = fb[(size_t)(jt + tid) * 3 + 0];
      sA[tid * 4 + 1] = fb[(size_t)(jt + tid) * 3 + 1];
      sA[tid * 4 + 2] = fb[(size_t)(jt + tid) * 3 + 2];
    }
    __syncthreads();

#pragma unroll
    for (int cc = 0; cc < 4; cc++) {
      float vq[4];
#pragma unroll
      for (int u = 0; u < 4; u++) {
        int jl = (cc * 4 + u) * 4 + q;
        float d0 = c0 - sA[jl * 4];
        float d1 = c1 - sA[jl * 4 + 1];
        float d2 = c2 - sA[jl * 4 + 2];
        vq[u] = -(d0 * d0 + d1 * d1 + d2 * d2);
      }
      float m4 = fmaxf(fmaxf(vq[0], vq[1]), fmaxf(vq[2], vq[3]));
      if (pk(m4, 0xFFF) > tv[0]) {
#pragma unroll
        for (int u = 0; u < 4; u++)
          pins16(pk(vq[u], jt + (cc * 4 + u) * 4 + q), tv);
      }
    }
  }

  int p = b * NTOT + row0 + r;
  int sub = js * 4 + q;  // 0..15
  unsigned* dst = cval + (size_t)p * CSLOT + sub * 16;
#pragma unroll
  for (int t4 = 0; t4 < 4; t4++) {
    uint4 o;
    o.x = tv[t4 * 4 + 0];
    o.y = tv[t4 * 4 + 1];
    o.z = tv[t4 * 4 + 2];
    o.w = tv[t4 * 4 + 3];
    *(uint4*)&dst[t4 * 4] = o;
  }
}

// ---------------- KNN stage 1 (C=64/128): pipelined global_load_lds ----------
// Double-buffered LDS (2x32KB), Dt (34.8KB) overlaid on buf1. Counted
// vmcnt(8): next chunk's 8 async loads stay in flight across barriers and
// across the Dt-scan phase (cross-jt prefetch). LDS layout XOR-swizzled
// ((row*64+quad*16)^((row&7)<<4)); gll writes linearly, so the swizzle is
// applied by inverse-permuting the per-lane GLOBAL source address.
template <int C>
__global__ __launch_bounds__(256, 2) void knn_m(const ushort* __restrict__ Xhi,
                                                const ushort* __restrict__ Xlo,
                                                const float* __restrict__ sqh,
                                                unsigned* __restrict__ cval) {
  constexpr int NK = C / 32;
  constexpr int NJT = NTOT / (128 * JSPLIT);
  __shared__ __align__(16) char smem[67584];
  float* Dt = (float*)(smem + 32768);  // 128*68 floats, overlays buf1

  int tid = threadIdx.x;
  int raw = blockIdx.x;
  int b = raw & 3;
  int js = (raw >> 3) & (JSPLIT - 1);
  int it = (((raw >> 6) & 15) << 1) | ((raw >> 2) & 1);
  int i0 = it * 128;
  const ushort* xh = Xhi + (size_t)b * NTOT * C;
  const ushort* xl = Xlo + (size_t)b * NTOT * C;

  int l = tid & 63, wid = tid >> 6;
  int wi = wid & 1, wj = wid >> 1;
  int n = l & 15, quad = l >> 4;
  int xl16 = (n & 7) << 4;  // fragment-read XOR (row&7 == n&7 for all frags)
  int selr = (wid << 5) | (l & 31);
  int sels = l >> 5;

  // lane -> (R,q) decode: chunk c = (R*4+q) ^ (R&7); invert for c = lane
  int c2b = (l >> 2) & 1, c3b = (l >> 3) & 1, c4b = (l >> 4) & 1, c5b = (l >> 5) & 1;
  int Rl = (c2b ^ c4b) | (c3b << 1) | (c4b << 2) | (c5b << 3);
  int ql = ((l & 1) ^ c2b ^ c4b) | ((((l >> 1) & 1) ^ c3b) << 1);

  // hoist all sqv loads; drain so the steady-state vmcnt counting is pure gll
  float sqv[NJT][4];
#pragma unroll
  for (int t = 0; t < NJT; t++)
#pragma unroll
    for (int tj = 0; tj < 4; tj++)
      sqv[t][tj] =
          sqh[b * NTOT + js * (NTOT / JSPLIT) + t * 128 + wj * 64 + tj * 16 + n];
  asm volatile("s_waitcnt vmcnt(0)" ::: "memory");

  unsigned tv[KSUB];
#pragma unroll
  for (int t = 0; t < KSUB; t++) tv[t] = 0u;

  // 8 gll calls per wave per chunk: 4 arrays x 2 sub-bands of 16 rows
  auto issue = [&](int jtn, int kcn, char* buf) {
    int j0n = js * (NTOT / JSPLIT) + jtn * 128;
#pragma unroll
    for (int c2 = 0; c2 < 2; c2++) {
      int R = Rl + (wid * 2 + c2) * 16;
      size_t gA = (size_t)(i0 + R) * C + kcn + ql * 8;
      size_t gB = (size_t)(j0n + R) * C + kcn + ql * 8;
      char* ld = buf + wid * 2048 + c2 * 1024;
      gll16(xh + gA, ld);            // Ah
      gll16(xl + gA, ld + 8192);     // Al
      gll16(xh + gB, ld + 16384);    // Bh
      gll16(xl + gB, ld + 24576);    // Bl
    }
  };

  issue(0, 0, smem);  // preamble: (jt0, kc0) -> buf0

  for (int jt = 0; jt < NJT; jt++) {
    int j0 = js * (NTOT / JSPLIT) + jt * 128;

    f32x4 acc[4][4];
#pragma unroll
    for (int ti = 0; ti < 4; ti++)
#pragma unroll
      for (int tj = 0; tj < 4; tj++) acc[ti][tj] = (f32x4)(0.f);

    for (int kc = 0; kc < NK; kc++) {
      __builtin_amdgcn_s_barrier();  // (A) prior readers of target buf done
      int njt = (kc + 1 < NK) ? jt : ((jt + 1 == NJT) ? 0 : jt + 1);
      int nkc = (kc + 1 < NK) ? (kc + 1) * 32 : 0;
      issue(njt, nkc, (kc & 1) ? smem : smem + 32768);
      asm volatile("s_waitcnt vmcnt(8)" ::: "memory");  // kc's 8 landed
      __builtin_amdgcn_s_barrier();                     // (C) all waves' data in
      const char* bc = (kc & 1) ? smem + 32768 : smem;

      bf16x8 ah[4], al_[4];
#pragma unroll
      for (int ti = 0; ti < 4; ti++) {
        int row = wi * 64 + ti * 16 + n;
        int off = (row * 64 + quad * 16) ^ xl16;
        ah[ti] = *(const bf16x8*)(bc + off);
        al_[ti] = *(const bf16x8*)(bc + 8192 + off);
      }
#pragma unroll
      for (int tj = 0; tj < 4; tj++) {
        int row = wj * 64 + tj * 16 + n;
        int off = (row * 64 + quad * 16) ^ xl16;
        bf16x8 bh = *(const bf16x8*)(bc + 16384 + off);
        bf16x8 bl = *(const bf16x8*)(bc + 24576 + off);
#pragma unroll
        for (int ti = 0; ti < 4; ti++) {
          acc[ti][tj] = __builtin_amdgcn_mfma_f32_16x16x32_bf16(ah[ti], bh, acc[ti][tj], 0, 0, 0);
          acc[ti][tj] = __builtin_amdgcn_mfma_f32_16x16x32_bf16(ah[ti], bl, acc[ti][tj], 0, 0, 0);
          acc[ti][tj] = __builtin_amdgcn_mfma_f32_16x16x32_bf16(al_[ti], bh, acc[ti][tj], 0, 0, 0);
        }
      }
    }
    __builtin_amdgcn_s_barrier();  // all waves done reading buf1 before Dt overlay

    // phase A: waves wj==0 hold j-cols 0..63
    if (wj == 0) {
#pragma unroll
      for (int ti = 0; ti < 4; ti++)
#pragma unroll
        for (int tj = 0; tj < 4; tj++) {
          float q = sqv[jt][tj];
#pragma unroll
          for (int r = 0; r < 4; r++)
            Dt[(wi * 64 + ti * 16 + quad * 4 + r) * 68 + tj * 16 + n] =
                acc[ti][tj][r] - q;
        }
    }
    asm volatile("s_waitcnt lgkmcnt(0)" ::: "memory");
    __builtin_amdgcn_s_barrier();
#pragma unroll
    for (int t4 = 0; t4 < 8; t4++) {
      float4 v = *(const float4*)&Dt[selr * 68 + sels * 32 + t4 * 4];
      float m4 = fmaxf(fmaxf(v.x, v.y), fmaxf(v.z, v.w));
      if (pk(m4, 0xFFF) > tv[0]) {
        int jb = j0 + sels * 32 + t4 * 4;
        pins16(pk(v.x, jb + 0), tv);
        pins16(pk(v.y, jb + 1), tv);
        pins16(pk(v.z, jb + 2), tv);
        pins16(pk(v.w, jb + 3), tv);
      }
    }
    __builtin_amdgcn_s_barrier();  // scanA reads consumed before phase-B writes
    // phase B: waves wj==1 hold j-cols 64..127
    if (wj == 1) {
#pragma unroll
      for (int ti = 0; ti < 4; ti++)
#pragma unroll
        for (int tj = 0; tj < 4; tj++) {
          float q = sqv[jt][tj];
#pragma unroll
          for (int r = 0; r < 4; r++)
            Dt[(wi * 64 + ti * 16 + quad * 4 + r) * 68 + tj * 16 + n] =
                acc[ti][tj][r] - q;
        }
    }
    asm volatile("s_waitcnt lgkmcnt(0)" ::: "memory");
    __builtin_amdgcn_s_barrier();
#pragma unroll
    for (int t4 = 0; t4 < 8; t4++) {
      float4 v = *(const float4*)&Dt[selr * 68 + sels * 32 + t4 * 4];
      float m4 = fmaxf(fmaxf(v.x, v.y), fmaxf(v.z, v.w));
      if (pk(m4, 0xFFF) > tv[0]) {
        int jb = j0 + 64 + sels * 32 + t4 * 4;
        pins16(pk(v.x, jb + 0), tv);
        pins16(pk(v.y, jb + 1), tv);
        pins16(pk(v.z, jb + 2), tv);
        pins16(pk(v.w, jb + 3), tv);
      }
    }
    // next iteration's barrier (A) protects Dt region vs the kc1 prefetch
  }

  int p = b * NTOT + i0 + selr;
  int sub = js * 2 + sels;  // 0..15
  unsigned* dst = cval + (size_t)p * CSLOT + sub * 16;
#pragma unroll
  for (int t4 = 0; t4 < 4; t4++) {
    uint4 o;
    o.x = tv[t4 * 4 + 0];
    o.y = tv[t4 * 4 + 1];
    o.z = tv[t4 * 4 + 2];
    o.w = tv[t4 * 4 + 3];
    *(uint4*)&dst[t4 * 4] = o;
  }
}

// ---------------- wave-per-point merge + exact refine ----------------
template <int C, int NC>
__global__ __launch_bounds__(256) void kref_w(const float* __restrict__ feat,
                                              const unsigned* __restrict__ cval,
                                              int* __restrict__ outidx) {
  int tid = threadIdx.x;
  int lane = tid & 63;
  int p = blockIdx.x * 4 + (tid >> 6);
  int b = p >> 12;
  int i = p & (NTOT - 1);
  const float* fb = feat + (size_t)b * NTOT * C;

  unsigned c0 = 0, c1 = 0, c2 = 0, c3 = 0;
  if (NC == 256) {
    uint4 cc = *(const uint4*)&cval[(size_t)p * CSLOT + lane * 4];
    c0 = cc.x;
    c1 = cc.y;
    c2 = cc.z;
    c3 = cc.w;
  } else {
    c0 = cval[(size_t)p * CSLOT + lane];
  }

  int jl[KMRG];
  int myj = -1;
#pragma unroll
  for (int t = 0; t < KMRG; t++) {
    unsigned m = max(max(c0, c1), max(c2, c3));
#pragma unroll
    for (int s = 1; s < 64; s <<= 1) m = max(m, (unsigned)__shfl_xor((int)m, s));
    jl[t] = (int)(m & 0xFFFu);
    if (lane == t) myj = (int)(m & 0xFFFu);
    if (c0 == m) c0 = 0;
    if (c1 == m) c1 = 0;
    if (c2 == m) c2 = 0;
    if (c3 == m) c3 = 0;
  }

  float myval = NEG_INF;
  if (C == 3) {
    if (lane < KMRG) {
      float x0 = fb[(size_t)i * 3 + 0];
      float x1 = fb[(size_t)i * 3 + 1];
      float x2 = fb[(size_t)i * 3 + 2];
      float y0 = fb[(size_t)myj * 3 + 0];
      float y1 = fb[(size_t)myj * 3 + 1];
      float y2 = fb[(size_t)myj * 3 + 2];
      float d0 = x0 - y0, d1 = x1 - y1, d2 = x2 - y2;
      myval = -(d0 * d0 + d1 * d1 + d2 * d2);
    }
  } else {
    constexpr int CPL = (C >= 64) ? C / 64 : 1;  // floats per lane
    float fx0, fx1 = 0.f;
    if (CPL == 2) {
      float2 xv = *(const float2*)&fb[(size_t)i * C + lane * 2];
      fx0 = xv.x;
      fx1 = xv.y;
    } else {
      fx0 = fb[(size_t)i * C + lane];
    }
#pragma unroll
    for (int u = 0; u < KMRG; u++) {
      int j = jl[u];
      float d;
      if (CPL == 2) {
        float2 yv = *(const float2*)&fb[(size_t)j * C + lane * 2];
        float dx = fx0 - yv.x, dy = fx1 - yv.y;
        d = dx * dx + dy * dy;
      } else {
        float y = fb[(size_t)j * C + lane];
        float dx = fx0 - y;
        d = dx * dx;
      }
#pragma unroll
      for (int s = 1; s < 64; s <<= 1) d += __shfl_xor(d, s);
      if (lane == u) myval = -d;
    }
  }

  // final exact top-20 across lanes (lane u holds candidate u)
  int wj = 0;
#pragma unroll
  for (int t = 0; t < KNN; t++) {
    float bv = myval;
    int bx = myj;
#pragma unroll
    for (int s = 1; s < 64; s <<= 1) {
      float ov = __shfl_xor(bv, s);
      int ox = __shfl_xor(bx, s);
      if (ov > bv || (ov == bv && ox < bx)) {
        bv = ov;
        bx = ox;
      }
    }
    if (lane == t) wj = bx;
    if (myj == bx) myval = NEG_INF;
  }
  if (lane < KNN) outidx[(size_t)p * KNN + lane] = wj;
}

// ---------------- 128x128 GEMM (K>=16): Y = A * Wc^T (+bias on V half) ------
__global__ __launch_bounds__(256) void gemm128(const float* __restrict__ A,
                                               const float* __restrict__ Wc,
                                               const float* __restrict__ bias,
                                               float* __restrict__ Y, int K, int N2,
                                               int O) {
  constexpr int P = 140;
  __shared__ float As[16 * P];
  __shared__ float Bs[16 * P];
  int tid = threadIdx.x;
  int n0 = blockIdx.x * 128;
  int m0 = blockIdx.y * 128;
  int tx = tid & 15, ty = tid >> 4;
  int aoff = (ty * 8) + (((ty * 8) >> 5) << 2);
  int boff = (tx * 8) + (((tx * 8) >> 5) << 2);
  float acc[8][8];
#pragma unroll
  for (int ii = 0; ii < 8; ii++)
#pragma unroll
    for (int jj = 0; jj < 8; jj++) acc[ii][jj] = 0.f;

  for (int kc = 0; kc < K; kc += 16) {
    __syncthreads();
#pragma unroll
    for (int l = 0; l < 2; l++) {
      int e = tid + 256 * l;
      int rr = e >> 2, c4 = e & 3;
      int sc = rr + ((rr >> 5) << 2);
      float4 va = *(const float4*)&A[(size_t)(m0 + rr) * K + kc + c4 * 4];
      As[(c4 * 4 + 0) * P + sc] = va.x;
      As[(c4 * 4 + 1) * P + sc] = va.y;
      As[(c4 * 4 + 2) * P + sc] = va.z;
      As[(c4 * 4 + 3) * P + sc] = va.w;
      float4 vb = *(const float4*)&Wc[(size_t)(n0 + rr) * K + kc + c4 * 4];
      Bs[(c4 * 4 + 0) * P + sc] = vb.x;
      Bs[(c4 * 4 + 1) * P + sc] = vb.y;
      Bs[(c4 * 4 + 2) * P + sc] = vb.z;
      Bs[(c4 * 4 + 3) * P + sc] = vb.w;
    }
    __syncthreads();
#pragma unroll 8
    for (int k = 0; k < 16; k++) {
      float4 a0 = *(const float4*)&As[k * P + aoff];
      float4 a1 = *(const float4*)&As[k * P + aoff + 4];
      float4 b0 = *(const float4*)&Bs[k * P + boff];
      float4 b1 = *(const float4*)&Bs[k * P + boff + 4];
      float av[8] = {a0.x, a0.y, a0.z, a0.w, a1.x, a1.y, a1.z, a1.w};
      float bv[8] = {b0.x, b0.y, b0.z, b0.w, b1.x, b1.y, b1.z, b1.w};
#pragma unroll
      for (int ii = 0; ii < 8; ii++)
#pragma unroll
        for (int jj = 0; jj < 8; jj++)
          acc[ii][jj] = fmaf(av[ii], bv[jj], acc[ii][jj]);
    }
  }

  int col0 = n0 + tx * 8;
  float bv[8];
#pragma unroll
  for (int jj = 0; jj < 8; jj++) {
    int col = col0 + jj;
    bv[jj] = (col >= O) ? bias[col - O] : 0.f;
  }
#pragma unroll
  for (int ii = 0; ii < 8; ii++) {
    int row = m0 + ty * 8 + ii;
    float4 o0, o1;
    o0.x = acc[ii][0] + bv[0];
    o0.y = acc[ii][1] + bv[1];
    o0.z = acc[ii][2] + bv[2];
    o0.w = acc[ii][3] + bv[3];
    o1.x = acc[ii][4] + bv[4];
    o1.y = acc[ii][5] + bv[5];
    o1.z = acc[ii][6] + bv[6];
    o1.w = acc[ii][7] + bv[7];
    *(float4*)&Y[(size_t)row * N2 + col0] = o0;
    *(float4*)&Y[(size_t)row * N2 + col0 + 4] = o1;
  }
}

// ---------------- small GEMM for layer 1 (K=3) ----------------
__global__ __launch_bounds__(256) void gemm_k(const float* __restrict__ A,
                                              const float* __restrict__ Wc,
                                              const float* __restrict__ bias,
                                              float* __restrict__ Y, int K, int N2,
                                              int O) {
  __shared__ float As[8 * 68];
  __shared__ float Bs[8 * 68];
  int tid = threadIdx.x;
  int n0 = blockIdx.x * 64;
  int m0 = blockIdx.y * 64;
  int tx = tid & 15, ty = tid >> 4;
  float acc[4][4] = {};
  for (int k0 = 0; k0 < K; k0 += 8) {
    __syncthreads();
    {
      int e = tid, mm = e >> 3, kk = e & 7;
      As[kk * 68 + mm] = (k0 + kk < K) ? A[(size_t)(m0 + mm) * K + k0 + kk] : 0.f;
      int nn = mm;
      Bs[kk * 68 + nn] = (k0 + kk < K) ? Wc[(size_t)(n0 + nn) * K + k0 + kk] : 0.f;
      e = tid + 256;
      mm = e >> 3;
      kk = e & 7;
      As[kk * 68 + mm] = (k0 + kk < K) ? A[(size_t)(m0 + mm) * K + k0 + kk] : 0.f;
      nn = mm;
      Bs[kk * 68 + nn] = (k0 + kk < K) ? Wc[(size_t)(n0 + nn) * K + k0 + kk] : 0.f;
    }
    __syncthreads();
#pragma unroll
    for (int kk = 0; kk < 8; kk++) {
      float4 av = *(float4*)&As[kk * 68 + ty * 4];
      float4 bv = *(float4*)&Bs[kk * 68 + tx * 4];
      float a[4] = {av.x, av.y, av.z, av.w};
      float bb2[4] = {bv.x, bv.y, bv.z, bv.w};
#pragma unroll
      for (int ii = 0; ii < 4; ii++)
#pragma unroll
        for (int jj = 0; jj < 4; jj++) acc[ii][jj] += a[ii] * bb2[jj];
    }
  }
  int col = n0 + tx * 4;
  bool isV = (col >= O);
  float b0 = 0.f, b1 = 0.f, b2 = 0.f, b3 = 0.f;
  if (isV) {
    b0 = bias[col + 0 - O];
    b1 = bias[col + 1 - O];
    b2 = bias[col + 2 - O];
    b3 = bias[col + 3 - O];
  }
#pragma unroll
  for (int ii = 0; ii < 4; ii++) {
    int row = m0 + ty * 4 + ii;
    float4 o4;
    o4.x = acc[ii][0] + b0;
    o4.y = acc[ii][1] + b1;
    o4.z = acc[ii][2] + b2;
    o4.w = acc[ii][3] + b3;
    *(float4*)&Y[(size_t)row * N2 + col] = o4;
  }
}

// ---------------- gather + max + LeakyReLU (float4) ----------------
template <int O>
__global__ __launch_bounds__(256) void gmax_v(const float* __restrict__ Y,
                                              const int* __restrict__ idx,
                                              float* __restrict__ out) {
  constexpr int T = O / 4;
  constexpr int G = 256 / T;
  int tid = threadIdx.x;
  int p = blockIdx.x * G + tid / T;
  int o4 = (tid % T) * 4;
  int b = p >> 12;
  constexpr int N2 = 2 * O;
  const int* ip = idx + (size_t)p * KNN;
  float4 m = make_float4(NEG_INF, NEG_INF, NEG_INF, NEG_INF);
#pragma unroll
  for (int k = 0; k < KNN; k++) {
    int j = ip[k];
    float4 v = *(const float4*)&Y[((size_t)(b * NTOT + j)) * N2 + o4];
    m.x = fmaxf(m.x, v.x);
    m.y = fmaxf(m.y, v.y);
    m.z = fmaxf(m.z, v.z);
    m.w = fmaxf(m.w, v.w);
  }
  float4 c = *(const float4*)&Y[(size_t)p * N2 + O + o4];
  float4 o;
  o.x = c.x + m.x;
  o.y = c.y + m.y;
  o.z = c.z + m.z;
  o.w = c.w + m.w;
  o.x = (o.x >= 0.f) ? o.x : 0.2f * o.x;
  o.y = (o.y >= 0.f) ? o.y : 0.2f * o.y;
  o.z = (o.z >= 0.f) ? o.z : 0.2f * o.z;
  o.w = (o.w >= 0.f) ? o.w : 0.2f * o.w;
  *(float4*)&out[(size_t)p * O + o4] = o;
}

// ---------------- host side ----------------
template <int C, int O>
static void run_layer(const float* fin, void* const* w5, float* fout, float* Wc,
                      float* biasb, int* idx, float* Y, float* sqh,
                      unsigned* cval, ushort* Xhi, ushort* Xlo,
                      hipStream_t stream) {
  const float* W = (const float*)w5[0];
  const float* g = (const float*)w5[1];
  const float* bb = (const float*)w5[2];
  const float* mm = (const float*)w5[3];
  const float* vv = (const float*)w5[4];
  int N2 = 2 * O;
  prep_w<<<(2 * O * C + 255) / 256, 256, 0, stream>>>(W, g, bb, mm, vv, Wc, biasb, O, C);
  if (C == 3) {
    knn3_g<<<NBATCH * 64 * JSPLIT3, 256, 0, stream>>>(fin, cval);
    kref_w<3, 256><<<NBATCH * NTOT / 4, 256, 0, stream>>>(fin, cval, idx);
    dim3 gg(N2 / 64, NBATCH * NTOT / 64);
    gemm_k<<<gg, 256, 0, stream>>>(fin, Wc, biasb, Y, C, N2, O);
  } else {
    constexpr int CC = (C == 3) ? 64 : C;
    cvt_k<<<NBATCH * NTOT * CC / 256, 256, 0, stream>>>(fin, Xhi, Xlo);
    sqh_k<CC><<<NBATCH * NTOT / 256, 256, 0, stream>>>(fin, sqh);
    knn_m<CC><<<NBATCH * 32 * JSPLIT, 256, 0, stream>>>(Xhi, Xlo, sqh, cval);
    kref_w<CC, 256><<<NBATCH * NTOT / 4, 256, 0, stream>>>(fin, cval, idx);
    dim3 gg(N2 / 128, NBATCH * NTOT / 128);
    gemm128<<<gg, 256, 0, stream>>>(fin, Wc, biasb, Y, C, N2, O);
  }
  gmax_v<O><<<NBATCH * NTOT / (256 / (O / 4)), 256, 0, stream>>>(Y, idx, fout);
}

extern "C" void kernel_launch(void* const* d_in, const int* in_sizes, int n_in,
                              void* d_out, int out_size, void* d_ws, size_t ws_size,
                              hipStream_t stream) {
  const float* x = (const float*)d_in[0];
  char* ws = (char*)d_ws;
  float* Wc = (float*)(ws + 0);            // 262144
  float* biasb = (float*)(ws + 262144);    // 1024
  int* idx = (int*)(ws + 263168);          // 1310720
  float* sqh = (float*)(ws + 1573888);     // 65536
  float* Y = (float*)(ws + 1639424);       // 33554432 -> ends 35193856
  float* x1 = (float*)(ws + 35193856);     // 4194304
  float* x2 = (float*)(ws + 39388160);     // 4194304
  float* x3 = (float*)(ws + 43582464);     // 8388608

  // aliases inside Y (all consumed by kref_w before gemm writes Y):
  unsigned* cval = (unsigned*)Y;                           // 16384*256*4 = 16777216
  ushort* Xhi = (ushort*)((char*)Y + 16777216);            // 4194304
  ushort* Xlo = (ushort*)((char*)Y + 16777216 + 4194304);  // 4194304

  float* outf = (float*)d_out;

  run_layer<3, 64>(x, d_in + 1, x1, Wc, biasb, idx, Y, sqh, cval, Xhi, Xlo, stream);
  run_layer<64, 64>(x1, d_in + 6, x2, Wc, biasb, idx, Y, sqh, cval, Xhi, Xlo, stream);
  run_layer<64, 128>(x2, d_in + 11, x3, Wc, biasb, idx, Y, sqh, cval, Xhi, Xlo, stream);
  run_layer<128, 256>(x3, d_in + 16, outf, Wc, biasb, idx, Y, sqh, cval, Xhi, Xlo, stream);
}